// Round 5
// baseline (93.012 us; speedup 1.0000x reference)
//
#include <hip/hip_runtime.h>
#include <hip/hip_bf16.h>
#include <stdint.h>

#define B_ 4
#define N_ 2000
#define T_ 12
#define D_ 64
#define K_ 3
#define DEG_ 8
#define E_ (N_*DEG_)              // 16000
#define ROWS_ (B_*N_*T_)          // 96000
#define NT_ (N_*T_)               // 24000
#define EPN_ (B_*T_*D_)           // 3072 elements per node row
#define V4PB_ (T_*D_/4)           // 192 vec4 per (node,b)
#define ROWBYTES_ (EPN_*4)        // 12288 bytes per node row
#define LOG2E_ 1.4426950408889634f

__device__ __forceinline__ uint32_t f32_to_bf16_bits(float x) {
    uint32_t u = __float_as_uint(x);
    return (u + 0x7FFFu + ((u >> 16) & 1u)) >> 16;   // RNE
}
__device__ __forceinline__ uint32_t pack2(float p, float f) {
    return (f32_to_bf16_bits(p) << 16) | f32_to_bf16_bits(f);
}

// ---------- Kernel 0: W' = log2e * (W_mlp @ W1),  b'' = log2e * (b_mlp @ W1) ----------
// (W1 = W_attn[:64]; W2/b_attn cancel inside the per-dst softmax; max-shift also
//  cancels, so mlp can pre-exponentiate: p = 2^(log2e*G1). gcn then needs NO exp.)
__global__ void wprime_kernel(const float* __restrict__ Wm,
                              const float* __restrict__ Wa,
                              const float* __restrict__ bm,
                              float* __restrict__ Wp,
                              float* __restrict__ bpp) {
    const int d = threadIdx.x;
    const int c = blockIdx.x;
    float s = 0.f;
    if (c < 64) {
        #pragma unroll
        for (int e = 0; e < 64; ++e) s += Wm[c*64 + e] * Wa[e*64 + d];
        Wp[c*64 + d] = s * LOG2E_;
    } else {
        #pragma unroll
        for (int e = 0; e < 64; ++e) s += bm[e] * Wa[e*64 + d];
        bpp[d] = s * LOG2E_;
    }
}

// ---------- Kernel 1: feats = X@Wm + bm ; p = exp2(X@W' + b'') ; pack bf16 pair ----------
__launch_bounds__(256)
__global__ void mlp_kernel(const float* __restrict__ input,
                           const float* __restrict__ Wm,
                           const float* __restrict__ bm,
                           const float* __restrict__ Wp,
                           const float* __restrict__ bpp,
                           uint32_t* __restrict__ packed) {
    __shared__ float sWm[64*64];
    __shared__ float sWp[64*64];
    __shared__ float sX[64*68];       // transposed [c][r], stride 68

    const int t = threadIdx.x;
    #pragma unroll
    for (int i = 0; i < 4; ++i) {
        ((float4*)sWm)[t + 256*i] = ((const float4*)Wm)[t + 256*i];
        ((float4*)sWp)[t + 256*i] = ((const float4*)Wp)[t + 256*i];
    }
    const size_t row0 = (size_t)blockIdx.x * 64;
    #pragma unroll
    for (int i = 0; i < 4; ++i) {
        int idx = t + 256*i;          // [0,1024)
        int r   = idx >> 4;           // row 0..63
        int c4  = idx & 15;           // float4 col chunk
        float4 v = ((const float4*)input)[(row0 + r)*16 + c4];
        sX[(c4*4+0)*68 + r] = v.x;
        sX[(c4*4+1)*68 + r] = v.y;
        sX[(c4*4+2)*68 + r] = v.z;
        sX[(c4*4+3)*68 + r] = v.w;
    }
    __syncthreads();

    const int rg = t >> 4, cg = t & 15;
    const int r0 = rg*4, c0 = cg*4;
    float aF[4][4] = {{0}}, aG[4][4] = {{0}};

    #pragma unroll
    for (int c = 0; c < 64; ++c) {
        float4 w  = *(const float4*)&sWm[c*64 + c0];
        float4 wp = *(const float4*)&sWp[c*64 + c0];
        float4 x  = *(const float4*)&sX [c*68 + r0];
        const float xr[4]  = {x.x, x.y, x.z, x.w};
        const float wq[4]  = {w.x, w.y, w.z, w.w};
        const float wpq[4] = {wp.x, wp.y, wp.z, wp.w};
        #pragma unroll
        for (int r = 0; r < 4; ++r)
            #pragma unroll
            for (int q = 0; q < 4; ++q) {
                aF[r][q] += xr[r]*wq[q];
                aG[r][q] += xr[r]*wpq[q];
            }
    }

    const float4 b4  = *(const float4*)&bm[c0];
    const float4 bp4 = *(const float4*)&bpp[c0];
    const float bq[4]  = {b4.x, b4.y, b4.z, b4.w};
    const float bpq[4] = {bp4.x, bp4.y, bp4.z, bp4.w};

    #pragma unroll
    for (int r = 0; r < 4; ++r) {
        const int g  = (int)row0 + r0 + r;       // global row -> (b,n,tt)
        const int b  = g / NT_;
        const int rm = g - b*NT_;
        const int n  = rm / T_;
        const int tt = rm - n*T_;
        uint32_t* dst = packed + (size_t)n*EPN_ + b*(T_*D_) + tt*D_ + c0;
        uint4 o;
        o.x = pack2(__builtin_amdgcn_exp2f(aG[r][0]+bpq[0]), aF[r][0]+bq[0]);
        o.y = pack2(__builtin_amdgcn_exp2f(aG[r][1]+bpq[1]), aF[r][1]+bq[1]);
        o.z = pack2(__builtin_amdgcn_exp2f(aG[r][2]+bpq[2]), aF[r][2]+bq[2]);
        o.w = pack2(__builtin_amdgcn_exp2f(aG[r][3]+bpq[3]), aF[r][3]+bq[3]);
        *(uint4*)dst = o;
    }
}

// ---------- Kernel 2: per-node 8-edge softmax aggregation, K graphs ----------
// Grid (N, 3). No LDS/barrier; edges+weight are uniform scalar loads. All 24
// gather loads hoisted into registers (saddr form: SGPR row base + shared
// voffset) so vmcnt staging overlaps k=1,2 latency under k=0 arithmetic.
// p = exp(logit) is precomputed in mlp: softmax = (sum p*f)/(sum p). No VALU trans.
__launch_bounds__(256, 4)
__global__ void gcn_kernel(const uint32_t* __restrict__ packed,
                           const float* __restrict__ input,
                           const int* __restrict__ edges,
                           const float* __restrict__ weight,
                           float* __restrict__ out) {
    const int n     = blockIdx.x;
    const int slice = blockIdx.y;
    const int t     = threadIdx.x;

    const int vv = slice*256 + t;      // vec4 index within node row [0,768)
    const int b  = vv / V4PB_;
    const int r4 = vv - b*V4PB_;
    const size_t off4 = (size_t)b*(NT_*D_/4) + (size_t)n*V4PB_ + r4;
    const float4 inv = ((const float4*)input)[off4];   // residual, issued early

    // ---- hoist ALL gather loads (3 graphs x 8 edges) ----
    uint4 pu[K_][8];
    #pragma unroll
    for (int k = 0; k < K_; ++k) {
        const int4 e0 = *(const int4*)(edges + (size_t)k*(2*E_) + n*DEG_);
        const int4 e1 = *(const int4*)(edges + (size_t)k*(2*E_) + n*DEG_ + 4);
        const int srcs[8] = {e0.x, e0.y, e0.z, e0.w, e1.x, e1.y, e1.z, e1.w};
        #pragma unroll
        for (int j = 0; j < 8; ++j) {
            const char* base = (const char*)packed
                             + (size_t)((uint32_t)srcs[j] * (uint32_t)ROWBYTES_);
            pu[k][j] = *(const uint4*)(base + (size_t)vv * 16);
        }
    }

    float acc[4] = {0.f, 0.f, 0.f, 0.f};
    #pragma unroll
    for (int k = 0; k < K_; ++k) {
        const float wk = weight[k];
        const uint32_t* pw = (const uint32_t*)&pu[k][0];
        #pragma unroll
        for (int q = 0; q < 4; ++q) {
            float s = 0.f, num = 0.f;
            #pragma unroll
            for (int j = 0; j < 8; ++j) {
                const uint32_t u = pw[j*4 + q];
                const float p = __uint_as_float(u & 0xFFFF0000u);  // exp(logit), bf16
                const float f = __uint_as_float(u << 16);          // feats, bf16
                s += p;
                num = fmaf(p, f, num);
            }
            acc[q] += wk * num * __builtin_amdgcn_rcpf(s);
        }
    }

    float4 o;
    o.x = (acc[0] > 0.f ? acc[0] : 0.01f*acc[0]) + inv.x;
    o.y = (acc[1] > 0.f ? acc[1] : 0.01f*acc[1]) + inv.y;
    o.z = (acc[2] > 0.f ? acc[2] : 0.01f*acc[2]) + inv.z;
    o.w = (acc[3] > 0.f ? acc[3] : 0.01f*acc[3]) + inv.w;
    ((float4*)out)[off4] = o;
}

extern "C" void kernel_launch(void* const* d_in, const int* in_sizes, int n_in,
                              void* d_out, int out_size, void* d_ws, size_t ws_size,
                              hipStream_t stream) {
    const float* input  = (const float*)d_in[0];
    const float* Wm     = (const float*)d_in[1];
    const float* bm     = (const float*)d_in[2];
    const float* Wa     = (const float*)d_in[3];
    // d_in[4] = b_attn (cancels inside per-dst softmax), unused
    const float* weight = (const float*)d_in[5];
    const int*   edges  = (const int*)d_in[6];
    float* out = (float*)d_out;
    uint32_t* packed = (uint32_t*)d_ws;     // [N][B][T][D] of (bf16 exp(logit) | bf16 feats)

    // W' and b'' scratch live in the head of d_out; gcn_kernel fully overwrites out afterwards.
    float* Wp  = (float*)d_out;
    float* bpp = (float*)d_out + 64*64;

    hipLaunchKernelGGL(wprime_kernel, dim3(65), dim3(64), 0, stream, Wm, Wa, bm, Wp, bpp);
    hipLaunchKernelGGL(mlp_kernel, dim3(ROWS_/64), dim3(256), 0, stream,
                       input, Wm, bm, Wp, bpp, packed);
    hipLaunchKernelGGL(gcn_kernel, dim3(N_, 3), dim3(256), 0, stream,
                       packed, input, edges, weight, out);
}

// Round 6
// 73.889 us; speedup vs baseline: 1.2588x; 1.2588x over previous
//
#include <hip/hip_runtime.h>
#include <hip/hip_bf16.h>
#include <stdint.h>

#define B_ 4
#define N_ 2000
#define T_ 12
#define D_ 64
#define K_ 3
#define DEG_ 8
#define E_ (N_*DEG_)              // 16000
#define ROWS_ (B_*N_*T_)          // 96000
#define NT_ (N_*T_)               // 24000
#define EPN_ (B_*T_*D_)           // 3072 elements per node row
#define V4PB_ (T_*D_/4)           // 192 vec4 per (node,b)
#define ROWBYTES_ (EPN_*4)        // 12288 bytes per node row
#define LOG2E_ 1.4426950408889634f

__device__ __forceinline__ uint32_t f32_to_bf16_bits(float x) {
    uint32_t u = __float_as_uint(x);
    return (u + 0x7FFFu + ((u >> 16) & 1u)) >> 16;   // RNE
}
__device__ __forceinline__ uint32_t pack2(float p, float f) {
    return (f32_to_bf16_bits(p) << 16) | f32_to_bf16_bits(f);
}

// ---------- Kernel 0: W' = log2e * (W_mlp @ W1),  b'' = log2e * (b_mlp @ W1) ----------
// (W1 = W_attn[:64]; W2/b_attn cancel inside the per-dst softmax; the max-shift also
//  cancels, so mlp can pre-exponentiate: p = 2^(log2e*G1). gcn then needs NO exp.)
__global__ void wprime_kernel(const float* __restrict__ Wm,
                              const float* __restrict__ Wa,
                              const float* __restrict__ bm,
                              float* __restrict__ Wp,
                              float* __restrict__ bpp) {
    const int d = threadIdx.x;
    const int c = blockIdx.x;
    float s = 0.f;
    if (c < 64) {
        #pragma unroll
        for (int e = 0; e < 64; ++e) s += Wm[c*64 + e] * Wa[e*64 + d];
        Wp[c*64 + d] = s * LOG2E_;
    } else {
        #pragma unroll
        for (int e = 0; e < 64; ++e) s += bm[e] * Wa[e*64 + d];
        bpp[d] = s * LOG2E_;
    }
}

// ---------- Kernel 1: feats = X@Wm + bm ; p = exp2(X@W' + b'') ; pack bf16 pair ----------
__launch_bounds__(256)
__global__ void mlp_kernel(const float* __restrict__ input,
                           const float* __restrict__ Wm,
                           const float* __restrict__ bm,
                           const float* __restrict__ Wp,
                           const float* __restrict__ bpp,
                           uint32_t* __restrict__ packed) {
    __shared__ float sWm[64*64];
    __shared__ float sWp[64*64];
    __shared__ float sX[64*68];       // transposed [c][r], stride 68

    const int t = threadIdx.x;
    #pragma unroll
    for (int i = 0; i < 4; ++i) {
        ((float4*)sWm)[t + 256*i] = ((const float4*)Wm)[t + 256*i];
        ((float4*)sWp)[t + 256*i] = ((const float4*)Wp)[t + 256*i];
    }
    const size_t row0 = (size_t)blockIdx.x * 64;
    #pragma unroll
    for (int i = 0; i < 4; ++i) {
        int idx = t + 256*i;          // [0,1024)
        int r   = idx >> 4;           // row 0..63
        int c4  = idx & 15;           // float4 col chunk
        float4 v = ((const float4*)input)[(row0 + r)*16 + c4];
        sX[(c4*4+0)*68 + r] = v.x;
        sX[(c4*4+1)*68 + r] = v.y;
        sX[(c4*4+2)*68 + r] = v.z;
        sX[(c4*4+3)*68 + r] = v.w;
    }
    __syncthreads();

    const int rg = t >> 4, cg = t & 15;
    const int r0 = rg*4, c0 = cg*4;
    float aF[4][4] = {{0}}, aG[4][4] = {{0}};

    #pragma unroll
    for (int c = 0; c < 64; ++c) {
        float4 w  = *(const float4*)&sWm[c*64 + c0];
        float4 wp = *(const float4*)&sWp[c*64 + c0];
        float4 x  = *(const float4*)&sX [c*68 + r0];
        const float xr[4]  = {x.x, x.y, x.z, x.w};
        const float wq[4]  = {w.x, w.y, w.z, w.w};
        const float wpq[4] = {wp.x, wp.y, wp.z, wp.w};
        #pragma unroll
        for (int r = 0; r < 4; ++r)
            #pragma unroll
            for (int q = 0; q < 4; ++q) {
                aF[r][q] += xr[r]*wq[q];
                aG[r][q] += xr[r]*wpq[q];
            }
    }

    const float4 b4  = *(const float4*)&bm[c0];
    const float4 bp4 = *(const float4*)&bpp[c0];
    const float bq[4]  = {b4.x, b4.y, b4.z, b4.w};
    const float bpq[4] = {bp4.x, bp4.y, bp4.z, bp4.w};

    #pragma unroll
    for (int r = 0; r < 4; ++r) {
        const int g  = (int)row0 + r0 + r;       // global row -> (b,n,tt)
        const int b  = g / NT_;
        const int rm = g - b*NT_;
        const int n  = rm / T_;
        const int tt = rm - n*T_;
        uint32_t* dst = packed + (size_t)n*EPN_ + b*(T_*D_) + tt*D_ + c0;
        uint4 o;
        o.x = pack2(__builtin_amdgcn_exp2f(aG[r][0]+bpq[0]), aF[r][0]+bq[0]);
        o.y = pack2(__builtin_amdgcn_exp2f(aG[r][1]+bpq[1]), aF[r][1]+bq[1]);
        o.z = pack2(__builtin_amdgcn_exp2f(aG[r][2]+bpq[2]), aF[r][2]+bq[2]);
        o.w = pack2(__builtin_amdgcn_exp2f(aG[r][3]+bpq[3]), aF[r][3]+bq[3]);
        *(uint4*)dst = o;
    }
}

// ---------- Kernel 2: per-node 8-edge softmax aggregation, K graphs ----------
// Grid (N, 12), 64-thread (1-wave) blocks. Phase-major sub-striping: all blocks
// of phase ss touch only a 2.05 MB byte-stripe of packed (1 KB per row), which
// fits every XCD's 4 MB L2 -> the 24x per-row gather reuse becomes L2 hits
// instead of L3 round trips (the round-4/5 latency wall). No LDS, no barrier;
// edges/weight are uniform scalar loads; p=exp(logit) precomputed in mlp.
__launch_bounds__(64, 4)
__global__ void gcn_kernel(const uint32_t* __restrict__ packed,
                           const float* __restrict__ input,
                           const int* __restrict__ edges,
                           const float* __restrict__ weight,
                           float* __restrict__ out) {
    const int n  = blockIdx.x;
    const int ss = blockIdx.y;            // sub-stripe phase [0,12)
    const int t  = threadIdx.x;           // 64 lanes

    const int vv = ss*64 + t;             // uint4 index within node row [0,768)
    const int b  = vv / V4PB_;            // 64 | 192, so one b per wave window
    const int r4 = vv - b*V4PB_;
    const size_t off4 = (size_t)b*(NT_*D_/4) + (size_t)n*V4PB_ + r4;
    const float4 inv = ((const float4*)input)[off4];   // residual, issued early

    float acc[4] = {0.f, 0.f, 0.f, 0.f};

    #pragma unroll
    for (int k = 0; k < K_; ++k) {
        const int4 e0 = *(const int4*)(edges + (size_t)k*(2*E_) + n*DEG_);
        const int4 e1 = *(const int4*)(edges + (size_t)k*(2*E_) + n*DEG_ + 4);
        const float wk = weight[k];
        const int srcs[8] = {e0.x, e0.y, e0.z, e0.w, e1.x, e1.y, e1.z, e1.w};

        uint4 pu[8];
        #pragma unroll
        for (int j = 0; j < 8; ++j) {
            const char* base = (const char*)packed
                             + (size_t)((uint32_t)srcs[j] * (uint32_t)ROWBYTES_);
            pu[j] = *(const uint4*)(base + (size_t)vv * 16);
        }

        #pragma unroll
        for (int q = 0; q < 4; ++q) {
            float s = 0.f, num = 0.f;
            #pragma unroll
            for (int j = 0; j < 8; ++j) {
                const uint32_t u = (q == 0) ? pu[j].x : (q == 1) ? pu[j].y
                                 : (q == 2) ? pu[j].z : pu[j].w;
                const float p = __uint_as_float(u & 0xFFFF0000u);  // exp(logit), bf16
                const float f = __uint_as_float(u << 16);          // feats, bf16
                s += p;
                num = fmaf(p, f, num);
            }
            acc[q] += wk * num * __builtin_amdgcn_rcpf(s);
        }
    }

    float4 o;
    o.x = (acc[0] > 0.f ? acc[0] : 0.01f*acc[0]) + inv.x;
    o.y = (acc[1] > 0.f ? acc[1] : 0.01f*acc[1]) + inv.y;
    o.z = (acc[2] > 0.f ? acc[2] : 0.01f*acc[2]) + inv.z;
    o.w = (acc[3] > 0.f ? acc[3] : 0.01f*acc[3]) + inv.w;
    ((float4*)out)[off4] = o;
}

extern "C" void kernel_launch(void* const* d_in, const int* in_sizes, int n_in,
                              void* d_out, int out_size, void* d_ws, size_t ws_size,
                              hipStream_t stream) {
    const float* input  = (const float*)d_in[0];
    const float* Wm     = (const float*)d_in[1];
    const float* bm     = (const float*)d_in[2];
    const float* Wa     = (const float*)d_in[3];
    // d_in[4] = b_attn (cancels inside per-dst softmax), unused
    const float* weight = (const float*)d_in[5];
    const int*   edges  = (const int*)d_in[6];
    float* out = (float*)d_out;
    uint32_t* packed = (uint32_t*)d_ws;     // [N][B][T][D] of (bf16 exp(logit) | bf16 feats)

    // W' and b'' scratch live in the head of d_out; gcn_kernel fully overwrites out afterwards.
    float* Wp  = (float*)d_out;
    float* bpp = (float*)d_out + 64*64;

    hipLaunchKernelGGL(wprime_kernel, dim3(65), dim3(64), 0, stream, Wm, Wa, bm, Wp, bpp);
    hipLaunchKernelGGL(mlp_kernel, dim3(ROWS_/64), dim3(256), 0, stream,
                       input, Wm, bm, Wp, bpp, packed);
    hipLaunchKernelGGL(gcn_kernel, dim3(N_, 12), dim3(64), 0, stream,
                       packed, input, edges, weight, out);
}

// Round 7
// 65.577 us; speedup vs baseline: 1.4184x; 1.1267x over previous
//
#include <hip/hip_runtime.h>
#include <hip/hip_bf16.h>
#include <stdint.h>

#define B_ 4
#define N_ 2000
#define T_ 12
#define D_ 64
#define K_ 3
#define DEG_ 8
#define E_ (N_*DEG_)              // 16000
#define ROWS_ (B_*N_*T_)          // 96000
#define NT_ (N_*T_)               // 24000
#define EPN_ (B_*T_*D_)           // 3072 elements per node row
#define V4PB_ (T_*D_/4)           // 192 vec4 per (node,b)
#define ROWBYTES_ (EPN_*4)        // 12288 bytes per node row
#define LOG2E_ 1.4426950408889634f

typedef __attribute__((ext_vector_type(8))) short short8v;   // 8 bf16 = 4 VGPR
typedef __attribute__((ext_vector_type(4))) float f32x4;     // MFMA acc

__device__ __forceinline__ uint32_t f32_to_bf16_bits(float x) {
    uint32_t u = __float_as_uint(x);
    return (u + 0x7FFFu + ((u >> 16) & 1u)) >> 16;   // RNE
}
__device__ __forceinline__ uint32_t pack2(float p, float f) {
    return (f32_to_bf16_bits(p) << 16) | f32_to_bf16_bits(f);
}

// ---------- Kernel 0 (prep): WB[c][k] = bf16( c<64 ? Wm[k][c] : log2e*(Wm@W1)[k][c-64] )
//            bpp[d] = log2e * (b_mlp @ W1)[d]        (W1 = W_attn[:64])
// W2/b_attn cancel inside the per-dst softmax; the max-shift also cancels, so
// the logit half can be pre-exponentiated downstream. WB is the MFMA B-operand
// (transposed, k-contiguous) and lives in the head of d_out (gcn overwrites it).
__global__ void prep_kernel(const float* __restrict__ Wm,
                            const float* __restrict__ Wa,
                            const float* __restrict__ bm,
                            uint16_t* __restrict__ WB,
                            float* __restrict__ bpp) {
    const int tk = threadIdx.x;          // k (or d for bias block)
    const int c  = blockIdx.x;           // 0..128
    if (c < 64) {
        WB[c*64 + tk] = (uint16_t)f32_to_bf16_bits(Wm[tk*64 + c]);
    } else if (c < 128) {
        const int cp = c - 64;
        float s = 0.f;
        #pragma unroll
        for (int e = 0; e < 64; ++e) s += Wm[tk*64 + e] * Wa[e*64 + cp];
        WB[c*64 + tk] = (uint16_t)f32_to_bf16_bits(s * LOG2E_);
    } else {
        float s = 0.f;
        #pragma unroll
        for (int e = 0; e < 64; ++e) s += bm[e] * Wa[e*64 + tk];
        bpp[tk] = s * LOG2E_;
    }
}

// ---------- Kernel 1: MFMA GEMM  [96000x64] @ [64x128] -> pack (exp2(logit), feat) ----------
// 64 rows/block, 4 waves; wave handles 16 rows x 128 cols = 8 col-tiles x 2 K-steps.
// A from global f32 (cvt to bf16 in-lane, disjoint 32B per lane), B from WB regs.
// No LDS, no barriers.
__launch_bounds__(256)
__global__ void mlp_mfma(const float* __restrict__ X,
                         const uint16_t* __restrict__ WB,
                         const float* __restrict__ bm,
                         const float* __restrict__ bpp,
                         uint32_t* __restrict__ packed) {
    const int t    = threadIdx.x;
    const int wave = t >> 6, lane = t & 63;
    const int r    = lane & 15, q = lane >> 4;

    // B fragments: lane holds W[k=s*32+q*8 .. +7][c=tile*16+r] (k-contiguous in WB)
    short8v bfrag[8][2];
    #pragma unroll
    for (int tile = 0; tile < 8; ++tile) {
        const int c = tile*16 + r;
        #pragma unroll
        for (int s = 0; s < 2; ++s)
            bfrag[tile][s] = *(const short8v*)(WB + c*64 + s*32 + q*8);
    }

    const int row0 = blockIdx.x*64 + wave*16;

    f32x4 acc[8];
    #pragma unroll
    for (int tile = 0; tile < 8; ++tile) acc[tile] = (f32x4){0.f,0.f,0.f,0.f};

    #pragma unroll
    for (int s = 0; s < 2; ++s) {
        const float* xp = X + (size_t)(row0 + r)*64 + s*32 + q*8;
        const float4 x0 = *(const float4*)xp;
        const float4 x1 = *(const float4*)(xp + 4);
        short8v af;
        af[0] = (short)f32_to_bf16_bits(x0.x);
        af[1] = (short)f32_to_bf16_bits(x0.y);
        af[2] = (short)f32_to_bf16_bits(x0.z);
        af[3] = (short)f32_to_bf16_bits(x0.w);
        af[4] = (short)f32_to_bf16_bits(x1.x);
        af[5] = (short)f32_to_bf16_bits(x1.y);
        af[6] = (short)f32_to_bf16_bits(x1.z);
        af[7] = (short)f32_to_bf16_bits(x1.w);
        #pragma unroll
        for (int tile = 0; tile < 8; ++tile)
            acc[tile] = __builtin_amdgcn_mfma_f32_16x16x32_bf16(
                            af, bfrag[tile][s], acc[tile], 0, 0, 0);
    }

    // Epilogue: C/D layout col=lane&15, row=(lane>>4)*4+reg (m89-verified).
    // Tile pair (tile, tile+4) = (feats col cf, logit col cf+64).
    #pragma unroll
    for (int tile = 0; tile < 4; ++tile) {
        const int cf  = tile*16 + r;
        const float bmv = bm[cf];
        const float bpv = bpp[cf];
        #pragma unroll
        for (int reg = 0; reg < 4; ++reg) {
            const float f = acc[tile][reg]   + bmv;
            const float g = acc[tile+4][reg] + bpv;
            const uint32_t u = pack2(__builtin_amdgcn_exp2f(g), f);
            const int gR = row0 + q*4 + reg;           // global row -> (b,n,tt)
            const int b  = gR / NT_;
            const int rm = gR - b*NT_;
            const int n  = rm / T_;
            const int tt = rm - n*T_;
            packed[(size_t)n*EPN_ + b*(T_*D_) + tt*D_ + cf] = u;
        }
    }
}

// ---------- Kernel 2: per-node 8-edge softmax aggregation, K graphs ----------
// Grid (N, 12), 64-thread (1-wave) blocks. Phase-major sub-striping: all blocks
// of phase ss touch only a 2.05 MB byte-stripe of packed (1 KB per row), which
// fits every XCD's 4 MB L2 -> the 24x per-row gather reuse becomes L2 hits
// instead of L3 round trips. No LDS/barrier; edges+weight uniform scalar loads;
// p = exp(logit) precomputed in mlp: softmax = (sum p*f)/(sum p).
__launch_bounds__(64, 4)
__global__ void gcn_kernel(const uint32_t* __restrict__ packed,
                           const float* __restrict__ input,
                           const int* __restrict__ edges,
                           const float* __restrict__ weight,
                           float* __restrict__ out) {
    const int n  = blockIdx.x;
    const int ss = blockIdx.y;            // sub-stripe phase [0,12)
    const int t  = threadIdx.x;           // 64 lanes

    const int vv = ss*64 + t;             // uint4 index within node row [0,768)
    const int b  = vv / V4PB_;
    const int r4 = vv - b*V4PB_;
    const size_t off4 = (size_t)b*(NT_*D_/4) + (size_t)n*V4PB_ + r4;
    const float4 inv = ((const float4*)input)[off4];   // residual, issued early

    float acc[4] = {0.f, 0.f, 0.f, 0.f};

    #pragma unroll
    for (int k = 0; k < K_; ++k) {
        const int4 e0 = *(const int4*)(edges + (size_t)k*(2*E_) + n*DEG_);
        const int4 e1 = *(const int4*)(edges + (size_t)k*(2*E_) + n*DEG_ + 4);
        const float wk = weight[k];
        const int srcs[8] = {e0.x, e0.y, e0.z, e0.w, e1.x, e1.y, e1.z, e1.w};

        uint4 pu[8];
        #pragma unroll
        for (int j = 0; j < 8; ++j) {
            const char* base = (const char*)packed
                             + (size_t)((uint32_t)srcs[j] * (uint32_t)ROWBYTES_);
            pu[j] = *(const uint4*)(base + (size_t)vv * 16);
        }

        #pragma unroll
        for (int qq = 0; qq < 4; ++qq) {
            float s = 0.f, num = 0.f;
            #pragma unroll
            for (int j = 0; j < 8; ++j) {
                const uint32_t u = (qq == 0) ? pu[j].x : (qq == 1) ? pu[j].y
                                 : (qq == 2) ? pu[j].z : pu[j].w;
                const float p = __uint_as_float(u & 0xFFFF0000u);  // exp(logit), bf16
                const float f = __uint_as_float(u << 16);          // feats, bf16
                s += p;
                num = fmaf(p, f, num);
            }
            acc[qq] += wk * num * __builtin_amdgcn_rcpf(s);
        }
    }

    float4 o;
    o.x = (acc[0] > 0.f ? acc[0] : 0.01f*acc[0]) + inv.x;
    o.y = (acc[1] > 0.f ? acc[1] : 0.01f*acc[1]) + inv.y;
    o.z = (acc[2] > 0.f ? acc[2] : 0.01f*acc[2]) + inv.z;
    o.w = (acc[3] > 0.f ? acc[3] : 0.01f*acc[3]) + inv.w;
    ((float4*)out)[off4] = o;
}

extern "C" void kernel_launch(void* const* d_in, const int* in_sizes, int n_in,
                              void* d_out, int out_size, void* d_ws, size_t ws_size,
                              hipStream_t stream) {
    const float* input  = (const float*)d_in[0];
    const float* Wm     = (const float*)d_in[1];
    const float* bm     = (const float*)d_in[2];
    const float* Wa     = (const float*)d_in[3];
    // d_in[4] = b_attn (cancels inside per-dst softmax), unused
    const float* weight = (const float*)d_in[5];
    const int*   edges  = (const int*)d_in[6];
    float* out = (float*)d_out;
    uint32_t* packed = (uint32_t*)d_ws;   // [N][B][T][D] of (bf16 exp(logit) | bf16 feats)

    // Prep scratch lives in the head of d_out; gcn_kernel fully overwrites out.
    uint16_t* WB  = (uint16_t*)d_out;             // 128 cols x 64 k bf16 = 16 KB
    float*    bpp = (float*)d_out + 4096;         // 64 floats

    hipLaunchKernelGGL(prep_kernel, dim3(129), dim3(64), 0, stream, Wm, Wa, bm, WB, bpp);
    hipLaunchKernelGGL(mlp_mfma, dim3(ROWS_/64), dim3(256), 0, stream,
                       input, WB, bm, bpp, packed);
    hipLaunchKernelGGL(gcn_kernel, dim3(N_, 12), dim3(64), 0, stream,
                       packed, input, edges, weight, out);
}